// Round 8
// baseline (6313.660 us; speedup 1.0000x reference)
//
#include <hip/hip_runtime.h>
#include <hip/hip_bf16.h>

// LSTM_Net round 8: per-wave decoupled pipelines + clock heaters.
// r3-r7 eliminated every sync MECHANISM (fences, store scatter, poll
// congestion, data volume, RMW fan-in); ~14us/round is mechanism-invariant.
// Remaining suspects, both attacked here:
//  (1) DVFS sag: kernel is ~95% idle -> GFX clock may drop ~4x, inflating
//      every latency link. 64 heater WGs run dependent-FMA chains until the
//      recurrence completes, pinning utilization/clocks.
//  (2) Chain links: removed ALL __syncthreads. Each wave owns a 16-row x
//      8-col pipeline: polls per-wave flags (row w of 96 producers), 26 MFMA
//      iters, fast exp2-based epilogue (no libm tanhf call), 256B sc1 store,
//      s_waitcnt vmcnt(0), own flag store. Publish path = one wave, no
//      barrier, no cross-wave drain.
// Flags: per layer int[4][128] (row = wave/M-tile, col = cb producer; pad
// cols 96..127 = INT_MAX). L0 wave w step s waits fL0[w][*] >= s; L1 step s
// waits fL0[w][*] >= s && fL1[w][*] >= s-1. Coherence unchanged: rings
// (first-touch reads), sc1 write-through stores, relaxed agent flag ops,
// compiler barrier after poll to pin load ordering. No fences.

#define B_  64
#define T_  256
#define IN_ 64
#define H_  768
#define G_  3072   // 4*H
#define K0_ 832    // IN_ + H_
#define K1_ 1536   // 2*H_
#define NWG0 96
#define NWGC 192   // compute WGs
#define NWGT 256   // total WGs (incl. 64 heaters)
#define SLOT_ (96 * 64 * 8)   // ring slot elements = 49152

typedef __bf16 bf16_t;
typedef bf16_t bf16x8 __attribute__((ext_vector_type(8)));
typedef float  f32x4  __attribute__((ext_vector_type(4)));

__device__ __forceinline__ unsigned short f2bf(float f) {
    union { float f; unsigned u; } v; v.f = f;
    unsigned r = v.u + 0x7FFFu + ((v.u >> 16) & 1u);
    return (unsigned short)(r >> 16);
}
// fast transcendentals: inputs here are tiny (|x| ~ 1e-2); 1-ulp exp2 + rcp
// approx give ~1e-7 rel error, negligible vs the 6e-4 output budget.
__device__ __forceinline__ float fast_sigm(float x) {
    float e = __builtin_amdgcn_exp2f(-1.44269504f * x);
    return __builtin_amdgcn_rcpf(1.0f + e);
}
__device__ __forceinline__ float fast_tanh(float x) {
    float e = __builtin_amdgcn_exp2f(2.88539008f * x);
    return (e - 1.0f) * __builtin_amdgcn_rcpf(e + 1.0f);
}
// dword store bypassing L1/L2 to the agent coherence point (MALL).
__device__ __forceinline__ void st_llc_u32(unsigned* p, unsigned v) {
    asm volatile("global_store_dword %0, %1, off sc1" :: "v"(p), "v"(v) : "memory");
}
#define MFMA16(a, b, c) __builtin_amdgcn_mfma_f32_16x16x32_bf16((a), (b), (c), 0, 0, 0)
#define AGENT_LD(p) __hip_atomic_load((p), __ATOMIC_RELAXED, __HIP_MEMORY_SCOPE_AGENT)

// ---------------- prep ----------------
__global__ __launch_bounds__(256) void prep_kernel(
    const float* __restrict__ x,
    const float* __restrict__ Wih0, const float* __restrict__ Whh0,
    const float* __restrict__ bih0, const float* __restrict__ bhh0,
    const float* __restrict__ Wih1, const float* __restrict__ Whh1,
    const float* __restrict__ bih1, const float* __restrict__ bhh1,
    unsigned short* __restrict__ xsT,    // [T][B][64]
    unsigned short* __restrict__ W0cat,  // [3072][832]
    unsigned short* __restrict__ W1cat,  // [3072][1536]
    float* __restrict__ bias0, float* __restrict__ bias1,
    int* __restrict__ flags)             // [1024]: fL0[4][128], fL1[4][128]
{
    int i = blockIdx.x * blockDim.x + threadIdx.x;
    int stride = gridDim.x * blockDim.x;
    for (int j = i; j < B_ * T_ * IN_; j += stride) {
        int b = j >> 14;
        int t = (j >> 6) & (T_ - 1);
        int k = j & (IN_ - 1);
        xsT[(((size_t)t * B_) + b) * IN_ + k] = f2bf(x[j] * (1.0f / 1.5f));
    }
    for (int j = i; j < G_ * IN_; j += stride) {
        int r = j >> 6; int k = j & 63;
        W0cat[(size_t)r * K0_ + k] = f2bf(Wih0[j]);
    }
    for (int j = i; j < G_ * H_; j += stride) {
        int r = j / H_; int k = j - r * H_;
        W0cat[(size_t)r * K0_ + IN_ + k] = f2bf(Whh0[j]);
        W1cat[(size_t)r * K1_ + k]       = f2bf(Wih1[j]);
        W1cat[(size_t)r * K1_ + H_ + k]  = f2bf(Whh1[j]);
    }
    for (int j = i; j < G_; j += stride) {
        bias0[j] = bih0[j] + bhh0[j];
        bias1[j] = bih1[j] + bhh1[j];
    }
    // real producer slots (col<96) start 0; pad cols always-satisfied.
    for (int j = i; j < 1024; j += stride)
        flags[j] = ((j & 127) < NWG0) ? 0 : 0x7FFFFFFF;
}

// ---------------- persistent wavefront recurrence ----------------
// h rings: [t][cb][row][8] bf16; cb = 8-col block, one per WG; wave = M-tile.
__global__ __launch_bounds__(256) void lstm_persistent(
    const unsigned short* __restrict__ xsT,
    const unsigned short* __restrict__ W0cat,
    const unsigned short* __restrict__ W1cat,
    const float* __restrict__ bias0, const float* __restrict__ bias1,
    unsigned short* __restrict__ h1ring,  // [T][96][64][8]
    unsigned short* __restrict__ h2ring,  // [T][96][64][8]
    float* __restrict__ hf32,             // [B][H] fp32 (t = T-1)
    int* __restrict__ flags)              // fL0 = flags, fL1 = flags+512
{
    __shared__ unsigned short ldsb[4][16][8];   // per-wave 16x8 output patch

    const int tid  = threadIdx.x;
    const int lane = tid & 63;
    const int wave = tid >> 6;
    const int wg   = blockIdx.x;

    // ---------------- heater WGs: pin clocks until recurrence done ---------
    if (wg >= NWGC) {
        float a = 1.0f + (float)wg * 1e-7f;
        const float b = 1.0000001f, c = 1e-9f;
        for (;;) {
            #pragma unroll
            for (int i = 0; i < 256; i++) a = __builtin_fmaf(a, b, c);
            asm volatile("" : "+v"(a));   // keep the chain alive
            int f0 = AGENT_LD(&flags[0]);
            int f1 = AGENT_LD(&flags[512]);
            if (f0 >= T_ && f1 >= T_) break;
        }
        return;
    }

    const bool isL1 = (wg >= NWG0);
    const int cb   = isL1 ? (wg - NWG0) : wg;
    const int c0   = cb * 8;
    const int frow = lane & 15;
    const int q    = lane >> 4;       // quad id 0..3
    const int kof  = q * 8;
    const int m0   = wave * 16;

    int* fL0 = flags;
    int* fL1 = flags + 512;
    const int p1 = wave * 128 + lane;             // poll idx 1 (cols 0..63)
    const int p2 = wave * 128 + 64 + (lane & 31); // poll idx 2 (64..95 + pad)

    const unsigned short* Wc = isL1 ? W1cat : W0cat;
    const int Kc = isL1 ? K1_ : K0_;
    int q0 = frow >> 3, col0 = c0 + (frow & 7);
    const unsigned short* Bp0 = Wc + (size_t)(q0 * H_ + col0) * Kc + kof;       // gates i,f
    const unsigned short* Bp1 = Wc + (size_t)((2 + q0) * H_ + col0) * Kc + kof; // gates g,o

    const float* bias = isL1 ? bias1 : bias0;
    const bool lowhalf = (lane & 15) < 8;
    const int ecol = c0 + (lane & 7);
    float bi = 0.f, bff = 0.f, bg = 0.f, bo = 0.f;
    if (lowhalf) {
        bi  = bias[0 * H_ + ecol];
        bff = bias[1 * H_ + ecol];
        bg  = bias[2 * H_ + ecol];
        bo  = bias[3 * H_ + ecol];
    }
    float creg[4] = {0.f, 0.f, 0.f, 0.f};

    const size_t aoff = (size_t)q * 512 + (size_t)(m0 + frow) * 8;
    const size_t stoff_e = (size_t)cb * 512 + (size_t)(m0 + (lane >> 2)) * 8
                         + (size_t)(lane & 3) * 2;
    int* myflag0 = &fL0[wave * 128 + cb];
    int* myflag1 = &fL1[wave * 128 + cb];

    if (!isL1) {
        // ------------- layer 0: superstep s computes t = s ------------------
        for (int s = 0; s < T_; ++s) {
            f32x4 acc0 = {0.f, 0.f, 0.f, 0.f};
            f32x4 acc1 = {0.f, 0.f, 0.f, 0.f};
            {   // xs contribution: independent of sync/h.
                const unsigned short* xsp =
                    xsT + ((size_t)s * B_ + m0 + frow) * IN_ + kof;
                #pragma unroll
                for (int ki = 0; ki < 2; ki++) {
                    bf16x8 a  = *(const bf16x8*)(xsp + ki * 32);
                    bf16x8 b0 = *(const bf16x8*)(Bp0 + ki * 32);
                    bf16x8 b1 = *(const bf16x8*)(Bp1 + ki * 32);
                    acc0 = MFMA16(a, b0, acc0);
                    acc1 = MFMA16(a, b1, acc1);
                }
            }
            if (s > 0) {
                for (;;) {   // this wave's row of producers >= s
                    int fa = AGENT_LD(&fL0[p1]);
                    int fb = AGENT_LD(&fL0[p2]);
                    if (__all(fa >= s && fb >= s)) break;
                    __builtin_amdgcn_s_sleep(1);
                }
                asm volatile("" ::: "memory");   // pin h loads after the poll
                const unsigned short* hr = h1ring + (size_t)(s - 1) * SLOT_ + aoff;
                #pragma unroll
                for (int kj = 0; kj < 24; kj++) {
                    bf16x8 a  = *(const bf16x8*)(hr + kj * 2048);
                    bf16x8 b0 = *(const bf16x8*)(Bp0 + (kj + 2) * 32);
                    bf16x8 b1 = *(const bf16x8*)(Bp1 + (kj + 2) * 32);
                    acc0 = MFMA16(a, b0, acc0);
                    acc1 = MFMA16(a, b1, acc1);
                }
            }
            f32x4 pacc0, pacc1;
            #pragma unroll
            for (int j = 0; j < 4; j++) {
                pacc0[j] = __shfl_xor(acc0[j], 8);
                pacc1[j] = __shfl_xor(acc1[j], 8);
            }
            if (lowhalf) {
                #pragma unroll
                for (int j = 0; j < 4; j++) {
                    float pi = acc0[j]  + bi;
                    float pf = pacc0[j] + bff;
                    float pg = acc1[j]  + bg;
                    float po = pacc1[j] + bo;
                    float cn = fast_sigm(pf) * creg[j] + fast_sigm(pi) * fast_tanh(pg);
                    float hn = fast_sigm(po) * fast_tanh(cn);
                    creg[j] = cn;
                    ldsb[wave][q * 4 + j][lane & 7] = f2bf(hn);
                }
            }
            // wave-internal DS ordering: read sees this wave's writes.
            unsigned v = ((const unsigned*)&ldsb[wave][0][0])[lane];
            st_llc_u32((unsigned*)(h1ring + (size_t)s * SLOT_ + stoff_e), v);
            asm volatile("s_waitcnt vmcnt(0)" ::: "memory");   // own 256B acked
            if (lane == 0) st_llc_u32((unsigned*)myflag0, (unsigned)(s + 1));
        }
    } else {
        // ------------- layer 1: superstep s computes t = s - 1 --------------
        for (int s = 1; s <= T_; ++s) {
            const int t = s - 1;
            for (;;) {   // fL0 row >= s (h1[t]) and fL1 row >= s-1 (h2[t-1])
                int fa = AGENT_LD(&fL0[p1]);
                int fb = AGENT_LD(&fL0[p2]);
                int ga = AGENT_LD(&fL1[p1]);
                int gb = AGENT_LD(&fL1[p2]);
                if (__all(fa >= s && fb >= s && ga >= s - 1 && gb >= s - 1))
                    break;
                __builtin_amdgcn_s_sleep(1);
            }
            asm volatile("" ::: "memory");
            f32x4 acc0 = {0.f, 0.f, 0.f, 0.f};
            f32x4 acc1 = {0.f, 0.f, 0.f, 0.f};
            const unsigned short* h1r = h1ring + (size_t)t * SLOT_ + aoff;
            #pragma unroll
            for (int ki = 0; ki < 24; ki++) {
                bf16x8 a  = *(const bf16x8*)(h1r + ki * 2048);
                bf16x8 b0 = *(const bf16x8*)(Bp0 + ki * 32);
                bf16x8 b1 = *(const bf16x8*)(Bp1 + ki * 32);
                acc0 = MFMA16(a, b0, acc0);
                acc1 = MFMA16(a, b1, acc1);
            }
            if (t > 0) {
                const unsigned short* h2r = h2ring + (size_t)(t - 1) * SLOT_ + aoff;
                #pragma unroll
                for (int ki = 0; ki < 24; ki++) {
                    bf16x8 a  = *(const bf16x8*)(h2r + ki * 2048);
                    bf16x8 b0 = *(const bf16x8*)(Bp0 + (ki + 24) * 32);
                    bf16x8 b1 = *(const bf16x8*)(Bp1 + (ki + 24) * 32);
                    acc0 = MFMA16(a, b0, acc0);
                    acc1 = MFMA16(a, b1, acc1);
                }
            }
            f32x4 pacc0, pacc1;
            #pragma unroll
            for (int j = 0; j < 4; j++) {
                pacc0[j] = __shfl_xor(acc0[j], 8);
                pacc1[j] = __shfl_xor(acc1[j], 8);
            }
            if (lowhalf) {
                #pragma unroll
                for (int j = 0; j < 4; j++) {
                    float pi = acc0[j]  + bi;
                    float pf = pacc0[j] + bff;
                    float pg = acc1[j]  + bg;
                    float po = pacc1[j] + bo;
                    float cn = fast_sigm(pf) * creg[j] + fast_sigm(pi) * fast_tanh(pg);
                    float hn = fast_sigm(po) * fast_tanh(cn);
                    creg[j] = cn;
                    ldsb[wave][q * 4 + j][lane & 7] = f2bf(hn);
                    if (t == T_ - 1)
                        hf32[(size_t)(m0 + q * 4 + j) * H_ + ecol] = hn;
                }
            }
            unsigned v = ((const unsigned*)&ldsb[wave][0][0])[lane];
            st_llc_u32((unsigned*)(h2ring + (size_t)t * SLOT_ + stoff_e), v);
            asm volatile("s_waitcnt vmcnt(0)" ::: "memory");
            if (lane == 0) st_llc_u32((unsigned*)myflag1, (unsigned)s);
        }
    }
}

// ---------------- head ----------------
__global__ __launch_bounds__(256) void head_kernel(
    const float* __restrict__ hlast,
    const float* __restrict__ W1, const float* __restrict__ b1,
    const float* __restrict__ W2, const float* __restrict__ b2,
    float* __restrict__ out)
{
    __shared__ float hs[H_];
    __shared__ float partial[4];
    int b = blockIdx.x;
    int tid = threadIdx.x;
    for (int j = tid; j < H_; j += 256) hs[j] = hlast[(size_t)b * H_ + j];
    __syncthreads();
    float z = 0.f;
    const float* w = W1 + (size_t)tid * H_;
    for (int j = 0; j < H_; j++) z += hs[j] * w[j];
    z += b1[tid];
    z = z / (1.0f + fabsf(z));
    float p = z * W2[tid];
    #pragma unroll
    for (int off = 32; off > 0; off >>= 1) p += __shfl_down(p, off, 64);
    if ((tid & 63) == 0) partial[tid >> 6] = p;
    __syncthreads();
    if (tid == 0) {
        float s = partial[0] + partial[1] + partial[2] + partial[3];
        out[b] = (s + b2[0]) * 70.0f;
    }
}

extern "C" void kernel_launch(void* const* d_in, const int* in_sizes, int n_in,
                              void* d_out, int out_size, void* d_ws, size_t ws_size,
                              hipStream_t stream) {
    const float* x    = (const float*)d_in[0];
    const float* Wih0 = (const float*)d_in[1];
    const float* Whh0 = (const float*)d_in[2];
    const float* bih0 = (const float*)d_in[3];
    const float* bhh0 = (const float*)d_in[4];
    const float* Wih1 = (const float*)d_in[5];
    const float* Whh1 = (const float*)d_in[6];
    const float* bih1 = (const float*)d_in[7];
    const float* bhh1 = (const float*)d_in[8];
    const float* W1   = (const float*)d_in[9];
    const float* b1   = (const float*)d_in[10];
    const float* W2   = (const float*)d_in[11];
    const float* b2   = (const float*)d_in[12];
    float* out = (float*)d_out;

    char* w = (char*)d_ws;
    int* flags = (int*)w;                         w += 4096;
    unsigned short* h1ring = (unsigned short*)w;  w += (size_t)T_ * SLOT_ * 2;
    unsigned short* h2ring = (unsigned short*)w;  w += (size_t)T_ * SLOT_ * 2;
    unsigned short* xsT    = (unsigned short*)w;  w += (size_t)B_ * T_ * IN_ * 2;
    unsigned short* W0cat  = (unsigned short*)w;  w += (size_t)G_ * K0_ * 2;
    unsigned short* W1cat  = (unsigned short*)w;  w += (size_t)G_ * K1_ * 2;
    float* bias0 = (float*)w;                     w += G_ * 4;
    float* bias1 = (float*)w;                     w += G_ * 4;
    float* hf32  = (float*)w;                     w += (size_t)B_ * H_ * 4;

    prep_kernel<<<1024, 256, 0, stream>>>(x, Wih0, Whh0, bih0, bhh0,
                                          Wih1, Whh1, bih1, bhh1,
                                          xsT, W0cat, W1cat, bias0, bias1, flags);
    lstm_persistent<<<NWGT, 256, 0, stream>>>(xsT, W0cat, W1cat, bias0, bias1,
                                              h1ring, h2ring, hf32, flags);
    head_kernel<<<B_, 256, 0, stream>>>(hf32, W1, b1, W2, b2, out);
}

// Round 9
// 3237.173 us; speedup vs baseline: 1.9504x; 1.9504x over previous
//
#include <hip/hip_runtime.h>
#include <hip/hip_bf16.h>

// LSTM_Net round 9: clean DVFS test = r5 kernel + properly-designed heaters.
// r8 was confounded: 16k heater threads polled two LIVE producer flag lines
// -> MALL congestion aimed at the sync path (24us/step). This round:
//   - base = r5 verbatim (best: 3565us; counter sync, packed rings, sc1
//     coalesced stores) + r8's exp2-based epilogue (absmax-neutral, faster).
//   - heaters (WG 192..255): dependent-FMA chains, poll a DEDICATED done
//     flag (ctrs[1536], written once at the end) every ~3.5us, lane0/wave
//     only -> ~zero MALL pressure on live lines.
// Hypothesis: the mechanism-invariant ~14us/superstep (r3-r7) is GFX clock
// sag on an idle-looking kernel (~4x inflation of every latency link; also
// explains 25-47ms first-after-idle outliers). Heaters pin the clock.

#define B_  64
#define T_  256
#define IN_ 64
#define H_  768
#define G_  3072   // 4*H
#define K0_ 832    // IN_ + H_
#define K1_ 1536   // 2*H_
#define NWG0 96
#define NWGC 192   // compute WGs
#define NWGT 256   // + 64 heater WGs
#define CB_  96
#define SLOT_ (CB_ * 64 * 8)   // ring slot elements = 49152

typedef __bf16 bf16_t;
typedef bf16_t bf16x8 __attribute__((ext_vector_type(8)));
typedef float  f32x4  __attribute__((ext_vector_type(4)));

__device__ __forceinline__ unsigned short f2bf(float f) {
    union { float f; unsigned u; } v; v.f = f;
    unsigned r = v.u + 0x7FFFu + ((v.u >> 16) & 1u);
    return (unsigned short)(r >> 16);
}
// fast transcendentals (1-ulp exp2 + rcp): ~1e-7 rel err at |x|~1e-2,
// negligible vs 6e-4 budget; verified absmax-neutral in r8.
__device__ __forceinline__ float fast_sigm(float x) {
    float e = __builtin_amdgcn_exp2f(-1.44269504f * x);
    return __builtin_amdgcn_rcpf(1.0f + e);
}
__device__ __forceinline__ float fast_tanh(float x) {
    float e = __builtin_amdgcn_exp2f(2.88539008f * x);
    return (e - 1.0f) * __builtin_amdgcn_rcpf(e + 1.0f);
}
__device__ __forceinline__ void st_llc_u32(unsigned* p, unsigned v) {
    asm volatile("global_store_dword %0, %1, off sc1" :: "v"(p), "v"(v) : "memory");
}
#define MFMA16(a, b, c) __builtin_amdgcn_mfma_f32_16x16x32_bf16((a), (b), (c), 0, 0, 0)
#define AGENT_LD(p) __hip_atomic_load((p), __ATOMIC_RELAXED, __HIP_MEMORY_SCOPE_AGENT)

// ---------------- prep ----------------
__global__ __launch_bounds__(256) void prep_kernel(
    const float* __restrict__ x,
    const float* __restrict__ Wih0, const float* __restrict__ Whh0,
    const float* __restrict__ bih0, const float* __restrict__ bhh0,
    const float* __restrict__ Wih1, const float* __restrict__ Whh1,
    const float* __restrict__ bih1, const float* __restrict__ bhh1,
    unsigned short* __restrict__ xsT,    // [T][B][64]
    unsigned short* __restrict__ W0cat,  // [3072][832]
    unsigned short* __restrict__ W1cat,  // [3072][1536]
    float* __restrict__ bias0, float* __restrict__ bias1,
    int* __restrict__ ctrs)              // [2048]: ctr0@0, ctr1@256, done@1536
{
    int i = blockIdx.x * blockDim.x + threadIdx.x;
    int stride = gridDim.x * blockDim.x;
    for (int j = i; j < B_ * T_ * IN_; j += stride) {
        int b = j >> 14;
        int t = (j >> 6) & (T_ - 1);
        int k = j & (IN_ - 1);
        xsT[(((size_t)t * B_) + b) * IN_ + k] = f2bf(x[j] * (1.0f / 1.5f));
    }
    for (int j = i; j < G_ * IN_; j += stride) {
        int r = j >> 6; int k = j & 63;
        W0cat[(size_t)r * K0_ + k] = f2bf(Wih0[j]);
    }
    for (int j = i; j < G_ * H_; j += stride) {
        int r = j / H_; int k = j - r * H_;
        W0cat[(size_t)r * K0_ + IN_ + k] = f2bf(Whh0[j]);
        W1cat[(size_t)r * K1_ + k]       = f2bf(Wih1[j]);
        W1cat[(size_t)r * K1_ + H_ + k]  = f2bf(Whh1[j]);
    }
    for (int j = i; j < G_; j += stride) {
        bias0[j] = bih0[j] + bhh0[j];
        bias1[j] = bih1[j] + bhh1[j];
    }
    for (int j = i; j < 2048; j += stride) ctrs[j] = 0;
}

// ---------------- persistent wavefront recurrence + heaters ----------------
// h rings: [t][cb][row][8] bf16; cb = col-block (8 cols), one per WG.
__global__ __launch_bounds__(256) void lstm_persistent(
    const unsigned short* __restrict__ xsT,
    const unsigned short* __restrict__ W0cat,
    const unsigned short* __restrict__ W1cat,
    const float* __restrict__ bias0, const float* __restrict__ bias1,
    unsigned short* __restrict__ h1ring,  // [T][96][64][8]
    unsigned short* __restrict__ h2ring,  // [T][96][64][8]
    float* __restrict__ hf32,             // [B][H] fp32 (t = T-1)
    int* __restrict__ ctrs)
{
    __shared__ unsigned short ldsb[4][16][8];   // per-wave 16x8 output patch

    const int tid  = threadIdx.x;
    const int lane = tid & 63;
    const int wave = tid >> 6;
    const int wg   = blockIdx.x;

    // ---------- heater WGs: pin GFX clock; poll DEDICATED done line --------
    if (wg >= NWGC) {
        int* done = &ctrs[1536];
        float a = 1.0f + (float)tid * 1e-7f;
        const float bm = 1.0000001f, cm = 1e-9f;
        for (;;) {
            for (int i = 0; i < 2048; i++)   // dependent chain, ~3.5us @2.4GHz
                a = __builtin_fmaf(a, bm, cm);
            asm volatile("" : "+v"(a));
            int d = 0;
            if (lane == 0) d = AGENT_LD(done);
            d = __builtin_amdgcn_readfirstlane(d);
            if (d != 0) break;
        }
        return;
    }

    const bool isL1 = (wg >= NWG0);
    const int cb   = isL1 ? (wg - NWG0) : wg;
    const int c0   = cb * 8;
    const int frow = lane & 15;
    const int q    = lane >> 4;       // quad id 0..3
    const int kof  = q * 8;
    const int m0   = wave * 16;

    int* ctr0 = &ctrs[0];
    int* ctr1 = &ctrs[256];

    const unsigned short* Wc = isL1 ? W1cat : W0cat;
    const int Kc = isL1 ? K1_ : K0_;
    int q0 = frow >> 3, col0 = c0 + (frow & 7);
    const unsigned short* Bp0 = Wc + (size_t)(q0 * H_ + col0) * Kc + kof;       // gates i,f
    const unsigned short* Bp1 = Wc + (size_t)((2 + q0) * H_ + col0) * Kc + kof; // gates g,o

    const float* bias = isL1 ? bias1 : bias0;
    const bool lowhalf = (lane & 15) < 8;
    const int ecol = c0 + (lane & 7);
    float bi = 0.f, bff = 0.f, bg = 0.f, bo = 0.f;
    if (lowhalf) {
        bi  = bias[0 * H_ + ecol];
        bff = bias[1 * H_ + ecol];
        bg  = bias[2 * H_ + ecol];
        bo  = bias[3 * H_ + ecol];
    }
    float creg[4] = {0.f, 0.f, 0.f, 0.f};

    const size_t aoff = (size_t)q * 512 + (size_t)(m0 + frow) * 8;
    const size_t stoff_e = (size_t)cb * 512 + (size_t)(m0 + (lane >> 2)) * 8
                         + (size_t)(lane & 3) * 2;

    if (!isL1) {
        // ------------- layer 0: superstep s computes t = s ------------------
        for (int s = 0; s < T_; ++s) {
            f32x4 acc0 = {0.f, 0.f, 0.f, 0.f};
            f32x4 acc1 = {0.f, 0.f, 0.f, 0.f};
            {   // xs contribution: independent of sync/h.
                const unsigned short* xsp =
                    xsT + ((size_t)s * B_ + m0 + frow) * IN_ + kof;
                #pragma unroll
                for (int ki = 0; ki < 2; ki++) {
                    bf16x8 a  = *(const bf16x8*)(xsp + ki * 32);
                    bf16x8 b0 = *(const bf16x8*)(Bp0 + ki * 32);
                    bf16x8 b1 = *(const bf16x8*)(Bp1 + ki * 32);
                    acc0 = MFMA16(a, b0, acc0);
                    acc1 = MFMA16(a, b1, acc1);
                }
            }
            if (s > 0) {
                if (tid == 0) {
                    while (AGENT_LD(ctr0) < NWG0 * s)
                        __builtin_amdgcn_s_sleep(1);
                }
                __syncthreads();
                const unsigned short* hr = h1ring + (size_t)(s - 1) * SLOT_ + aoff;
                #pragma unroll
                for (int kj = 0; kj < 24; kj++) {
                    bf16x8 a  = *(const bf16x8*)(hr + kj * 2048);
                    bf16x8 b0 = *(const bf16x8*)(Bp0 + (kj + 2) * 32);
                    bf16x8 b1 = *(const bf16x8*)(Bp1 + (kj + 2) * 32);
                    acc0 = MFMA16(a, b0, acc0);
                    acc1 = MFMA16(a, b1, acc1);
                }
            }
            f32x4 pacc0, pacc1;
            #pragma unroll
            for (int j = 0; j < 4; j++) {
                pacc0[j] = __shfl_xor(acc0[j], 8);
                pacc1[j] = __shfl_xor(acc1[j], 8);
            }
            if (lowhalf) {
                #pragma unroll
                for (int j = 0; j < 4; j++) {
                    float pi = acc0[j]  + bi;
                    float pf = pacc0[j] + bff;
                    float pg = acc1[j]  + bg;
                    float po = pacc1[j] + bo;
                    float cn = fast_sigm(pf) * creg[j] + fast_sigm(pi) * fast_tanh(pg);
                    float hn = fast_sigm(po) * fast_tanh(cn);
                    creg[j] = cn;
                    ldsb[wave][q * 4 + j][lane & 7] = f2bf(hn);
                }
            }
            unsigned v = ((const unsigned*)&ldsb[wave][0][0])[lane];
            st_llc_u32((unsigned*)(h1ring + (size_t)s * SLOT_ + stoff_e), v);
            __syncthreads();   // vmcnt(0) drain: h stores at coherence point
            if (tid == 0) atomicAdd(ctr0, 1);
        }
    } else {
        // ------------- layer 1: superstep s computes t = s - 1 --------------
        for (int s = 1; s <= T_; ++s) {
            const int t = s - 1;
            if (tid == 0) {
                while (AGENT_LD(ctr0) < NWG0 * s)
                    __builtin_amdgcn_s_sleep(1);
            }
            if (tid == 64 && t > 0) {
                while (AGENT_LD(ctr1) < NWG0 * t)
                    __builtin_amdgcn_s_sleep(1);
            }
            __syncthreads();
            f32x4 acc0 = {0.f, 0.f, 0.f, 0.f};
            f32x4 acc1 = {0.f, 0.f, 0.f, 0.f};
            const unsigned short* h1r = h1ring + (size_t)t * SLOT_ + aoff;
            #pragma unroll
            for (int ki = 0; ki < 24; ki++) {
                bf16x8 a  = *(const bf16x8*)(h1r + ki * 2048);
                bf16x8 b0 = *(const bf16x8*)(Bp0 + ki * 32);
                bf16x8 b1 = *(const bf16x8*)(Bp1 + ki * 32);
                acc0 = MFMA16(a, b0, acc0);
                acc1 = MFMA16(a, b1, acc1);
            }
            if (t > 0) {
                const unsigned short* h2r = h2ring + (size_t)(t - 1) * SLOT_ + aoff;
                #pragma unroll
                for (int ki = 0; ki < 24; ki++) {
                    bf16x8 a  = *(const bf16x8*)(h2r + ki * 2048);
                    bf16x8 b0 = *(const bf16x8*)(Bp0 + (ki + 24) * 32);
                    bf16x8 b1 = *(const bf16x8*)(Bp1 + (ki + 24) * 32);
                    acc0 = MFMA16(a, b0, acc0);
                    acc1 = MFMA16(a, b1, acc1);
                }
            }
            f32x4 pacc0, pacc1;
            #pragma unroll
            for (int j = 0; j < 4; j++) {
                pacc0[j] = __shfl_xor(acc0[j], 8);
                pacc1[j] = __shfl_xor(acc1[j], 8);
            }
            if (lowhalf) {
                #pragma unroll
                for (int j = 0; j < 4; j++) {
                    int row = m0 + q * 4 + j;
                    float pi = acc0[j]  + bi;
                    float pf = pacc0[j] + bff;
                    float pg = acc1[j]  + bg;
                    float po = pacc1[j] + bo;
                    float cn = fast_sigm(pf) * creg[j] + fast_sigm(pi) * fast_tanh(pg);
                    float hn = fast_sigm(po) * fast_tanh(cn);
                    creg[j] = cn;
                    ldsb[wave][q * 4 + j][lane & 7] = f2bf(hn);
                    if (t == T_ - 1) hf32[(size_t)row * H_ + ecol] = hn;
                }
            }
            unsigned v = ((const unsigned*)&ldsb[wave][0][0])[lane];
            st_llc_u32((unsigned*)(h2ring + (size_t)t * SLOT_ + stoff_e), v);
            __syncthreads();
            if (tid == 0) atomicAdd(ctr1, 1);
        }
        // signal heaters: recurrence complete (written by all 96 L1 WGs, ok)
        if (tid == 0) st_llc_u32((unsigned*)&ctrs[1536], 1u);
    }
}

// ---------------- head ----------------
__global__ __launch_bounds__(256) void head_kernel(
    const float* __restrict__ hlast,
    const float* __restrict__ W1, const float* __restrict__ b1,
    const float* __restrict__ W2, const float* __restrict__ b2,
    float* __restrict__ out)
{
    __shared__ float hs[H_];
    __shared__ float partial[4];
    int b = blockIdx.x;
    int tid = threadIdx.x;
    for (int j = tid; j < H_; j += 256) hs[j] = hlast[(size_t)b * H_ + j];
    __syncthreads();
    float z = 0.f;
    const float* w = W1 + (size_t)tid * H_;
    for (int j = 0; j < H_; j++) z += hs[j] * w[j];
    z += b1[tid];
    z = z / (1.0f + fabsf(z));
    float p = z * W2[tid];
    #pragma unroll
    for (int off = 32; off > 0; off >>= 1) p += __shfl_down(p, off, 64);
    if ((tid & 63) == 0) partial[tid >> 6] = p;
    __syncthreads();
    if (tid == 0) {
        float s = partial[0] + partial[1] + partial[2] + partial[3];
        out[b] = (s + b2[0]) * 70.0f;
    }
}

extern "C" void kernel_launch(void* const* d_in, const int* in_sizes, int n_in,
                              void* d_out, int out_size, void* d_ws, size_t ws_size,
                              hipStream_t stream) {
    const float* x    = (const float*)d_in[0];
    const float* Wih0 = (const float*)d_in[1];
    const float* Whh0 = (const float*)d_in[2];
    const float* bih0 = (const float*)d_in[3];
    const float* bhh0 = (const float*)d_in[4];
    const float* Wih1 = (const float*)d_in[5];
    const float* Whh1 = (const float*)d_in[6];
    const float* bih1 = (const float*)d_in[7];
    const float* bhh1 = (const float*)d_in[8];
    const float* W1   = (const float*)d_in[9];
    const float* b1   = (const float*)d_in[10];
    const float* W2   = (const float*)d_in[11];
    const float* b2   = (const float*)d_in[12];
    float* out = (float*)d_out;

    char* w = (char*)d_ws;
    int* ctrs = (int*)w;                          w += 8192;
    unsigned short* h1ring = (unsigned short*)w;  w += (size_t)T_ * SLOT_ * 2;
    unsigned short* h2ring = (unsigned short*)w;  w += (size_t)T_ * SLOT_ * 2;
    unsigned short* xsT    = (unsigned short*)w;  w += (size_t)B_ * T_ * IN_ * 2;
    unsigned short* W0cat  = (unsigned short*)w;  w += (size_t)G_ * K0_ * 2;
    unsigned short* W1cat  = (unsigned short*)w;  w += (size_t)G_ * K1_ * 2;
    float* bias0 = (float*)w;                     w += G_ * 4;
    float* bias1 = (float*)w;                     w += G_ * 4;
    float* hf32  = (float*)w;                     w += (size_t)B_ * H_ * 4;

    prep_kernel<<<1024, 256, 0, stream>>>(x, Wih0, Whh0, bih0, bhh0,
                                          Wih1, Whh1, bih1, bhh1,
                                          xsT, W0cat, W1cat, bias0, bias1, ctrs);
    lstm_persistent<<<NWGT, 256, 0, stream>>>(xsT, W0cat, W1cat, bias0, bias1,
                                              h1ring, h2ring, hf32, ctrs);
    head_kernel<<<B_, 256, 0, stream>>>(hf32, W1, b1, W2, b2, out);
}

// Round 10
// 3165.989 us; speedup vs baseline: 1.9942x; 1.0225x over previous
//
#include <hip/hip_runtime.h>
#include <hip/hip_bf16.h>

// LSTM_Net round 10: aggregator-tree sync (clean RMW-serialization test).
// r9: heaters+fast-epilogue -> 12.3us/step (from 13.9). Residual theory:
// 96 same-line atomicAdds serialized at the MALL (~100ns each ~ 10us/step).
// r7's "refutation" of this was confounded (192 scanning waves congested the
// flag lines). This round removes BOTH contended paths:
//   producers: fire-and-forget sc1 flag stores (per-WG slot, 6 lines, no RMW)
//   aggregators: WG192 (L0) / WG193 (L1), one wave scans the 96 flags (sole
//     reader) and broadcasts the completed epoch to 8 replicated lines
//   consumers: tid0/tid64 poll ONE replica line (wg&7), <=12 pollers/line
// Everything else = r9 verbatim (packed rings, coalesced sc1 h stores, fast
// exp2 epilogue, heaters on dedicated done line, no fences).

#define B_  64
#define T_  256
#define IN_ 64
#define H_  768
#define G_  3072   // 4*H
#define K0_ 832    // IN_ + H_
#define K1_ 1536   // 2*H_
#define NWG0 96
#define NWGC 192   // compute WGs
#define NWGT 256   // + 2 aggregators + 62 heaters
#define CB_  96
#define SLOT_ (CB_ * 64 * 8)   // ring slot elements = 49152

typedef __bf16 bf16_t;
typedef bf16_t bf16x8 __attribute__((ext_vector_type(8)));
typedef float  f32x4  __attribute__((ext_vector_type(4)));

__device__ __forceinline__ unsigned short f2bf(float f) {
    union { float f; unsigned u; } v; v.f = f;
    unsigned r = v.u + 0x7FFFu + ((v.u >> 16) & 1u);
    return (unsigned short)(r >> 16);
}
__device__ __forceinline__ float fast_sigm(float x) {
    float e = __builtin_amdgcn_exp2f(-1.44269504f * x);
    return __builtin_amdgcn_rcpf(1.0f + e);
}
__device__ __forceinline__ float fast_tanh(float x) {
    float e = __builtin_amdgcn_exp2f(2.88539008f * x);
    return (e - 1.0f) * __builtin_amdgcn_rcpf(e + 1.0f);
}
__device__ __forceinline__ void st_llc_u32(unsigned* p, unsigned v) {
    asm volatile("global_store_dword %0, %1, off sc1" :: "v"(p), "v"(v) : "memory");
}
#define MFMA16(a, b, c) __builtin_amdgcn_mfma_f32_16x16x32_bf16((a), (b), (c), 0, 0, 0)
#define AGENT_LD(p) __hip_atomic_load((p), __ATOMIC_RELAXED, __HIP_MEMORY_SCOPE_AGENT)

// ctrs layout (ints): flags0[0..95], flags1[256..351],
// ep0 replicas at 512+i*16 (i<8), ep1 replicas at 768+i*16, done at 1536.

// ---------------- prep ----------------
__global__ __launch_bounds__(256) void prep_kernel(
    const float* __restrict__ x,
    const float* __restrict__ Wih0, const float* __restrict__ Whh0,
    const float* __restrict__ bih0, const float* __restrict__ bhh0,
    const float* __restrict__ Wih1, const float* __restrict__ Whh1,
    const float* __restrict__ bih1, const float* __restrict__ bhh1,
    unsigned short* __restrict__ xsT,    // [T][B][64]
    unsigned short* __restrict__ W0cat,  // [3072][832]
    unsigned short* __restrict__ W1cat,  // [3072][1536]
    float* __restrict__ bias0, float* __restrict__ bias1,
    int* __restrict__ ctrs)              // [2048]
{
    int i = blockIdx.x * blockDim.x + threadIdx.x;
    int stride = gridDim.x * blockDim.x;
    for (int j = i; j < B_ * T_ * IN_; j += stride) {
        int b = j >> 14;
        int t = (j >> 6) & (T_ - 1);
        int k = j & (IN_ - 1);
        xsT[(((size_t)t * B_) + b) * IN_ + k] = f2bf(x[j] * (1.0f / 1.5f));
    }
    for (int j = i; j < G_ * IN_; j += stride) {
        int r = j >> 6; int k = j & 63;
        W0cat[(size_t)r * K0_ + k] = f2bf(Wih0[j]);
    }
    for (int j = i; j < G_ * H_; j += stride) {
        int r = j / H_; int k = j - r * H_;
        W0cat[(size_t)r * K0_ + IN_ + k] = f2bf(Whh0[j]);
        W1cat[(size_t)r * K1_ + k]       = f2bf(Wih1[j]);
        W1cat[(size_t)r * K1_ + H_ + k]  = f2bf(Whh1[j]);
    }
    for (int j = i; j < G_; j += stride) {
        bias0[j] = bih0[j] + bhh0[j];
        bias1[j] = bih1[j] + bhh1[j];
    }
    for (int j = i; j < 2048; j += stride) ctrs[j] = 0;
}

// ---------------- persistent wavefront recurrence ----------------
__global__ __launch_bounds__(256) void lstm_persistent(
    const unsigned short* __restrict__ xsT,
    const unsigned short* __restrict__ W0cat,
    const unsigned short* __restrict__ W1cat,
    const float* __restrict__ bias0, const float* __restrict__ bias1,
    unsigned short* __restrict__ h1ring,  // [T][96][64][8]
    unsigned short* __restrict__ h2ring,  // [T][96][64][8]
    float* __restrict__ hf32,             // [B][H] fp32 (t = T-1)
    int* __restrict__ ctrs)
{
    __shared__ unsigned short ldsb[4][16][8];

    const int tid  = threadIdx.x;
    const int lane = tid & 63;
    const int wave = tid >> 6;
    const int wg   = blockIdx.x;

    int* flags0 = &ctrs[0];
    int* flags1 = &ctrs[256];
    int* ep0    = &ctrs[512];   // replica i at ep0[i*16]
    int* ep1    = &ctrs[768];
    int* done   = &ctrs[1536];

    // ---------- aggregator WGs: scan flags, broadcast epochs ----------------
    if (wg == NWGC || wg == NWGC + 1) {
        if (wave != 0) return;
        const bool agg1 = (wg == NWGC + 1);
        int* fl = agg1 ? flags1 : flags0;
        int* ep = agg1 ? ep1 : ep0;
        const int i1 = lane;              // 0..63
        const int i2 = 64 + (lane & 31);  // 64..95
        for (int e = 1; e <= T_; ++e) {
            for (;;) {
                int fa = AGENT_LD(&fl[i1]);
                int fb = AGENT_LD(&fl[i2]);
                if (__all(fa >= e && fb >= e)) break;
                __builtin_amdgcn_s_sleep(1);
            }
            if (lane < 8) st_llc_u32((unsigned*)&ep[lane * 16], (unsigned)e);
        }
        if (agg1 && lane == 0) st_llc_u32((unsigned*)done, 1u);
        return;
    }
    // ---------- heater WGs: pin GFX clock; poll dedicated done line ---------
    if (wg > NWGC + 1) {
        float a = 1.0f + (float)tid * 1e-7f;
        const float bm = 1.0000001f, cm = 1e-9f;
        for (;;) {
            for (int i = 0; i < 2048; i++)
                a = __builtin_fmaf(a, bm, cm);
            asm volatile("" : "+v"(a));
            int d = 0;
            if (lane == 0) d = AGENT_LD(done);
            d = __builtin_amdgcn_readfirstlane(d);
            if (d != 0) break;
        }
        return;
    }

    const bool isL1 = (wg >= NWG0);
    const int cb   = isL1 ? (wg - NWG0) : wg;
    const int c0   = cb * 8;
    const int frow = lane & 15;
    const int q    = lane >> 4;
    const int kof  = q * 8;
    const int m0   = wave * 16;

    int* myrep0 = &ep0[(wg & 7) * 16];
    int* myrep1 = &ep1[(wg & 7) * 16];

    const unsigned short* Wc = isL1 ? W1cat : W0cat;
    const int Kc = isL1 ? K1_ : K0_;
    int q0 = frow >> 3, col0 = c0 + (frow & 7);
    const unsigned short* Bp0 = Wc + (size_t)(q0 * H_ + col0) * Kc + kof;       // gates i,f
    const unsigned short* Bp1 = Wc + (size_t)((2 + q0) * H_ + col0) * Kc + kof; // gates g,o

    const float* bias = isL1 ? bias1 : bias0;
    const bool lowhalf = (lane & 15) < 8;
    const int ecol = c0 + (lane & 7);
    float bi = 0.f, bff = 0.f, bg = 0.f, bo = 0.f;
    if (lowhalf) {
        bi  = bias[0 * H_ + ecol];
        bff = bias[1 * H_ + ecol];
        bg  = bias[2 * H_ + ecol];
        bo  = bias[3 * H_ + ecol];
    }
    float creg[4] = {0.f, 0.f, 0.f, 0.f};

    const size_t aoff = (size_t)q * 512 + (size_t)(m0 + frow) * 8;
    const size_t stoff_e = (size_t)cb * 512 + (size_t)(m0 + (lane >> 2)) * 8
                         + (size_t)(lane & 3) * 2;

    if (!isL1) {
        // ------------- layer 0: superstep s computes t = s ------------------
        for (int s = 0; s < T_; ++s) {
            f32x4 acc0 = {0.f, 0.f, 0.f, 0.f};
            f32x4 acc1 = {0.f, 0.f, 0.f, 0.f};
            {
                const unsigned short* xsp =
                    xsT + ((size_t)s * B_ + m0 + frow) * IN_ + kof;
                #pragma unroll
                for (int ki = 0; ki < 2; ki++) {
                    bf16x8 a  = *(const bf16x8*)(xsp + ki * 32);
                    bf16x8 b0 = *(const bf16x8*)(Bp0 + ki * 32);
                    bf16x8 b1 = *(const bf16x8*)(Bp1 + ki * 32);
                    acc0 = MFMA16(a, b0, acc0);
                    acc1 = MFMA16(a, b1, acc1);
                }
            }
            if (s > 0) {
                if (tid == 0) {   // epoch s = h1[s-1] fully published
                    while (AGENT_LD(myrep0) < s)
                        __builtin_amdgcn_s_sleep(1);
                }
                __syncthreads();
                const unsigned short* hr = h1ring + (size_t)(s - 1) * SLOT_ + aoff;
                #pragma unroll
                for (int kj = 0; kj < 24; kj++) {
                    bf16x8 a  = *(const bf16x8*)(hr + kj * 2048);
                    bf16x8 b0 = *(const bf16x8*)(Bp0 + (kj + 2) * 32);
                    bf16x8 b1 = *(const bf16x8*)(Bp1 + (kj + 2) * 32);
                    acc0 = MFMA16(a, b0, acc0);
                    acc1 = MFMA16(a, b1, acc1);
                }
            }
            f32x4 pacc0, pacc1;
            #pragma unroll
            for (int j = 0; j < 4; j++) {
                pacc0[j] = __shfl_xor(acc0[j], 8);
                pacc1[j] = __shfl_xor(acc1[j], 8);
            }
            if (lowhalf) {
                #pragma unroll
                for (int j = 0; j < 4; j++) {
                    float pi = acc0[j]  + bi;
                    float pf = pacc0[j] + bff;
                    float pg = acc1[j]  + bg;
                    float po = pacc1[j] + bo;
                    float cn = fast_sigm(pf) * creg[j] + fast_sigm(pi) * fast_tanh(pg);
                    float hn = fast_sigm(po) * fast_tanh(cn);
                    creg[j] = cn;
                    ldsb[wave][q * 4 + j][lane & 7] = f2bf(hn);
                }
            }
            unsigned v = ((const unsigned*)&ldsb[wave][0][0])[lane];
            st_llc_u32((unsigned*)(h1ring + (size_t)s * SLOT_ + stoff_e), v);
            __syncthreads();   // vmcnt(0) drain: h stores at coherence point
            if (tid == 0) st_llc_u32((unsigned*)&flags0[cb], (unsigned)(s + 1));
        }
    } else {
        // ------------- layer 1: superstep s computes t = s - 1 --------------
        for (int s = 1; s <= T_; ++s) {
            const int t = s - 1;
            if (tid == 0) {   // h1[t] ready at ep0 >= t+1 = s
                while (AGENT_LD(myrep0) < s)
                    __builtin_amdgcn_s_sleep(1);
            }
            if (tid == 64 && t > 0) {   // h2[t-1] ready at ep1 >= t
                while (AGENT_LD(myrep1) < t)
                    __builtin_amdgcn_s_sleep(1);
            }
            __syncthreads();
            f32x4 acc0 = {0.f, 0.f, 0.f, 0.f};
            f32x4 acc1 = {0.f, 0.f, 0.f, 0.f};
            const unsigned short* h1r = h1ring + (size_t)t * SLOT_ + aoff;
            #pragma unroll
            for (int ki = 0; ki < 24; ki++) {
                bf16x8 a  = *(const bf16x8*)(h1r + ki * 2048);
                bf16x8 b0 = *(const bf16x8*)(Bp0 + ki * 32);
                bf16x8 b1 = *(const bf16x8*)(Bp1 + ki * 32);
                acc0 = MFMA16(a, b0, acc0);
                acc1 = MFMA16(a, b1, acc1);
            }
            if (t > 0) {
                const unsigned short* h2r = h2ring + (size_t)(t - 1) * SLOT_ + aoff;
                #pragma unroll
                for (int ki = 0; ki < 24; ki++) {
                    bf16x8 a  = *(const bf16x8*)(h2r + ki * 2048);
                    bf16x8 b0 = *(const bf16x8*)(Bp0 + (ki + 24) * 32);
                    bf16x8 b1 = *(const bf16x8*)(Bp1 + (ki + 24) * 32);
                    acc0 = MFMA16(a, b0, acc0);
                    acc1 = MFMA16(a, b1, acc1);
                }
            }
            f32x4 pacc0, pacc1;
            #pragma unroll
            for (int j = 0; j < 4; j++) {
                pacc0[j] = __shfl_xor(acc0[j], 8);
                pacc1[j] = __shfl_xor(acc1[j], 8);
            }
            if (lowhalf) {
                #pragma unroll
                for (int j = 0; j < 4; j++) {
                    int row = m0 + q * 4 + j;
                    float pi = acc0[j]  + bi;
                    float pf = pacc0[j] + bff;
                    float pg = acc1[j]  + bg;
                    float po = pacc1[j] + bo;
                    float cn = fast_sigm(pf) * creg[j] + fast_sigm(pi) * fast_tanh(pg);
                    float hn = fast_sigm(po) * fast_tanh(cn);
                    creg[j] = cn;
                    ldsb[wave][q * 4 + j][lane & 7] = f2bf(hn);
                    if (t == T_ - 1) hf32[(size_t)row * H_ + ecol] = hn;
                }
            }
            unsigned v = ((const unsigned*)&ldsb[wave][0][0])[lane];
            st_llc_u32((unsigned*)(h2ring + (size_t)t * SLOT_ + stoff_e), v);
            __syncthreads();
            if (tid == 0) st_llc_u32((unsigned*)&flags1[cb], (unsigned)s);
        }
    }
}

// ---------------- head ----------------
__global__ __launch_bounds__(256) void head_kernel(
    const float* __restrict__ hlast,
    const float* __restrict__ W1, const float* __restrict__ b1,
    const float* __restrict__ W2, const float* __restrict__ b2,
    float* __restrict__ out)
{
    __shared__ float hs[H_];
    __shared__ float partial[4];
    int b = blockIdx.x;
    int tid = threadIdx.x;
    for (int j = tid; j < H_; j += 256) hs[j] = hlast[(size_t)b * H_ + j];
    __syncthreads();
    float z = 0.f;
    const float* w = W1 + (size_t)tid * H_;
    for (int j = 0; j < H_; j++) z += hs[j] * w[j];
    z += b1[tid];
    z = z / (1.0f + fabsf(z));
    float p = z * W2[tid];
    #pragma unroll
    for (int off = 32; off > 0; off >>= 1) p += __shfl_down(p, off, 64);
    if ((tid & 63) == 0) partial[tid >> 6] = p;
    __syncthreads();
    if (tid == 0) {
        float s = partial[0] + partial[1] + partial[2] + partial[3];
        out[b] = (s + b2[0]) * 70.0f;
    }
}

extern "C" void kernel_launch(void* const* d_in, const int* in_sizes, int n_in,
                              void* d_out, int out_size, void* d_ws, size_t ws_size,
                              hipStream_t stream) {
    const float* x    = (const float*)d_in[0];
    const float* Wih0 = (const float*)d_in[1];
    const float* Whh0 = (const float*)d_in[2];
    const float* bih0 = (const float*)d_in[3];
    const float* bhh0 = (const float*)d_in[4];
    const float* Wih1 = (const float*)d_in[5];
    const float* Whh1 = (const float*)d_in[6];
    const float* bih1 = (const float*)d_in[7];
    const float* bhh1 = (const float*)d_in[8];
    const float* W1   = (const float*)d_in[9];
    const float* b1   = (const float*)d_in[10];
    const float* W2   = (const float*)d_in[11];
    const float* b2   = (const float*)d_in[12];
    float* out = (float*)d_out;

    char* w = (char*)d_ws;
    int* ctrs = (int*)w;                          w += 8192;
    unsigned short* h1ring = (unsigned short*)w;  w += (size_t)T_ * SLOT_ * 2;
    unsigned short* h2ring = (unsigned short*)w;  w += (size_t)T_ * SLOT_ * 2;
    unsigned short* xsT    = (unsigned short*)w;  w += (size_t)B_ * T_ * IN_ * 2;
    unsigned short* W0cat  = (unsigned short*)w;  w += (size_t)G_ * K0_ * 2;
    unsigned short* W1cat  = (unsigned short*)w;  w += (size_t)G_ * K1_ * 2;
    float* bias0 = (float*)w;                     w += G_ * 4;
    float* bias1 = (float*)w;                     w += G_ * 4;
    float* hf32  = (float*)w;                     w += (size_t)B_ * H_ * 4;

    prep_kernel<<<1024, 256, 0, stream>>>(x, Wih0, Whh0, bih0, bhh0,
                                          Wih1, Whh1, bih1, bhh1,
                                          xsT, W0cat, W1cat, bias0, bias1, ctrs);
    lstm_persistent<<<NWGT, 256, 0, stream>>>(xsT, W0cat, W1cat, bias0, bias1,
                                              h1ring, h2ring, hf32, ctrs);
    head_kernel<<<B_, 256, 0, stream>>>(hf32, W1, b1, W2, b2, out);
}